// Round 9
// baseline (366.663 us; speedup 1.0000x reference)
//
#include <hip/hip_runtime.h>
#include <float.h>

// B_=1024 windows, N=64, M=128, H=8, D=32, DIM=256, nW=256
// rel bias index: rel = n - m + 128 in [1,191]
// masks: wi in {0,1} -> mask_left[wi], wi in {254,255} -> mask_right[wi-254]

typedef __attribute__((ext_vector_type(8))) short bf16x8;
typedef __attribute__((ext_vector_type(4))) float f32x4;

static __device__ __forceinline__ unsigned int f2bf(float f) {
    unsigned int u = __float_as_uint(f);
    return (u + 0x7FFFu + ((u >> 16) & 1u)) >> 16;  // RNE
}
static __device__ __forceinline__ unsigned int pack2(float lo, float hi) {
    return f2bf(lo) | (f2bf(hi) << 16);
}

// Pre-swizzled bf16 weight tile images. Each 128x32 W-tile is stored as its exact
// 8 KiB LDS image (Ws[col][k] bf16, byte ^= ((col&3)<<4) within the 64-B row) so
// kernel staging is a linear 16 B/lane copy. Regions (shorts): q @0, kv @65536, proj @196608.
__device__ unsigned short g_Wt[262144];

__global__ __launch_bounds__(256) void prep_wt(
    const float* __restrict__ q_w, const float* __restrict__ kv_w, const float* __restrict__ proj_w)
{
    const int gid = blockIdx.x * 256 + threadIdx.x;
    int rel, ncs; const float* src;
    if (gid < 65536)       { rel = gid;          src = q_w;    ncs = 256; }
    else if (gid < 196608) { rel = gid - 65536;  src = kv_w;   ncs = 512; }
    else                   { rel = gid - 196608; src = proj_w; ncs = 256; }
    const int tl = rel >> 12, i = rel & 4095;      // tile = ct*8 + ks ; i = short idx in tile
    const int ct = tl >> 3,  ks = tl & 7;
    const int col = i >> 5,  si = i & 31;
    const int kl = ((2 * si) ^ ((col & 3) << 4)) >> 1;   // inverse swizzle (bits 4-5 only) -> source k
    g_Wt[gid] = (unsigned short)f2bf(src[(ks * 32 + kl) * ncs + ct * 128 + col]);
}

// ---------- pipelined MFMA GEMM: C[rows x NC] = A[rows x 256] @ W + bias ----------
// Tile 128x128, BK=32, dbuf LDS 32 KiB -> 3 blocks/CU. 512 threads = 8 waves (2x4),
// wave tile 64x32. 8 K-steps, 1 barrier/step, 2-step register lookahead.
// XCD swizzle: all col-tiles of a row-tile on one XCD (A L2-shared, fetched ~once).
template<int NC, int WT_OFF, bool ABF16, bool F32OUT>
__global__ __launch_bounds__(512, 6) void gemm_p(
    const void* __restrict__ Ain, const float* __restrict__ bias, void* __restrict__ Cout)
{
    constexpr int NBN = NC / 128;
    __shared__ __align__(16) unsigned short As[2][4096];   // [buf][128 rows][32 k]
    __shared__ __align__(16) unsigned short Ws[2][4096];   // [buf] pre-swizzled tile image

    const int nbx = 8 * NBN;
    const int g = blockIdx.x / nbx, r = blockIdx.x % nbx;
    const int bn = r >> 3, bm = g * 8 + (r & 7);
    const size_t r0 = (size_t)bm * 128;
    const int c0 = bn * 128;

    const int t = threadIdx.x;
    const int wave = t >> 6, lane = t & 63;
    const int lr = lane & 15, hi = lane >> 4;
    const int rw = (wave >> 2) * 64, cw = (wave & 3) * 32;

    const int srow = t >> 2, sseg = t & 3;                       // A staging: row, 8-elem k-seg
    const int aoff = (16 * sseg) ^ ((srow & 3) << 4);            // swizzled byte off in 64B row

    f32x4 acc[4][2];
    #pragma unroll
    for (int i = 0; i < 4; ++i)
        #pragma unroll
        for (int j = 0; j < 2; ++j) acc[i][j] = (f32x4){0.f, 0.f, 0.f, 0.f};

    float4 raA[2], raB[2];   // f32 A staging (2-deep)
    uint4  rb16[2];          // bf16 A staging
    uint4  rwv[2];           // W staging

#define GLOAD(P, S)                                                                        \
    {                                                                                      \
        rwv[P] = *(const uint4*)(g_Wt + WT_OFF + ((size_t)(bn * 8 + (S)) << 12) + t * 8);  \
        if (ABF16) {                                                                       \
            rb16[P] = *(const uint4*)((const unsigned short*)Ain + (r0 + srow) * 256 + (S) * 32 + sseg * 8); \
        } else {                                                                           \
            const float* asrc = (const float*)Ain + (r0 + srow) * 256 + (S) * 32 + sseg * 8; \
            raA[P] = *(const float4*)asrc; raB[P] = *(const float4*)(asrc + 4);            \
        }                                                                                  \
    }

#define SWRITE(P, B)                                                                       \
    {                                                                                      \
        uint4 u;                                                                           \
        if (ABF16) u = rb16[P];                                                            \
        else u = make_uint4(pack2(raA[P].x, raA[P].y), pack2(raA[P].z, raA[P].w),          \
                            pack2(raB[P].x, raB[P].y), pack2(raB[P].z, raB[P].w));         \
        *(uint4*)((char*)As[B] + srow * 64 + aoff) = u;                                    \
        *(uint4*)((char*)Ws[B] + t * 16) = rwv[P];                                         \
    }

#define COMPUTE(B)                                                                         \
    {                                                                                      \
        const char* Ab = (const char*)As[B];                                               \
        const char* Wb = (const char*)Ws[B];                                               \
        const int ko = (16 * hi) ^ ((lr & 3) << 4);                                        \
        bf16x8 af0 = *(const bf16x8*)(Ab + (rw +      lr) * 64 + ko);                      \
        bf16x8 af1 = *(const bf16x8*)(Ab + (rw + 16 + lr) * 64 + ko);                      \
        bf16x8 af2 = *(const bf16x8*)(Ab + (rw + 32 + lr) * 64 + ko);                      \
        bf16x8 af3 = *(const bf16x8*)(Ab + (rw + 48 + lr) * 64 + ko);                      \
        bf16x8 bg0 = *(const bf16x8*)(Wb + (cw +      lr) * 64 + ko);                      \
        bf16x8 bg1 = *(const bf16x8*)(Wb + (cw + 16 + lr) * 64 + ko);                      \
        acc[0][0] = __builtin_amdgcn_mfma_f32_16x16x32_bf16(af0, bg0, acc[0][0], 0, 0, 0); \
        acc[0][1] = __builtin_amdgcn_mfma_f32_16x16x32_bf16(af0, bg1, acc[0][1], 0, 0, 0); \
        acc[1][0] = __builtin_amdgcn_mfma_f32_16x16x32_bf16(af1, bg0, acc[1][0], 0, 0, 0); \
        acc[1][1] = __builtin_amdgcn_mfma_f32_16x16x32_bf16(af1, bg1, acc[1][1], 0, 0, 0); \
        acc[2][0] = __builtin_amdgcn_mfma_f32_16x16x32_bf16(af2, bg0, acc[2][0], 0, 0, 0); \
        acc[2][1] = __builtin_amdgcn_mfma_f32_16x16x32_bf16(af2, bg1, acc[2][1], 0, 0, 0); \
        acc[3][0] = __builtin_amdgcn_mfma_f32_16x16x32_bf16(af3, bg0, acc[3][0], 0, 0, 0); \
        acc[3][1] = __builtin_amdgcn_mfma_f32_16x16x32_bf16(af3, bg1, acc[3][1], 0, 0, 0); \
    }

    GLOAD(0, 0); GLOAD(1, 1);        // both prologue loads in flight together
    SWRITE(0, 0); SWRITE(1, 1);
    __syncthreads();

    #pragma unroll 8
    for (int s = 0; s < 8; ++s) {
        const int cur = s & 1;
        if (s < 6) GLOAD(cur, s + 2);        // issue early: covered by compute + barrier + TLP
        COMPUTE(cur);
        if (s < 7) __syncthreads();          // all waves done reading buf cur
        if (s < 6) SWRITE(cur, cur);         // refill cur for step s+2 (visible via s+1's barrier)
    }

#undef GLOAD
#undef SWRITE
#undef COMPUTE

    // epilogue: row = r0+rw+i*16+4*hi+q, col = c0+cw+bj*16+lr
    #pragma unroll
    for (int i = 0; i < 4; ++i) {
        #pragma unroll
        for (int bj = 0; bj < 2; ++bj) {
            const int col = c0 + cw + bj * 16 + lr;
            const float bb = bias[col];
            #pragma unroll
            for (int q = 0; q < 4; ++q) {
                const size_t row = r0 + rw + i * 16 + 4 * hi + q;
                const float val = acc[i][bj][q] + bb;
                if (F32OUT) ((float*)Cout)[row * NC + col] = val;
                else        ((unsigned short*)Cout)[row * NC + col] = (unsigned short)f2bf(val);
            }
        }
    }
}

// ---------- fused MFMA attention: one block per WINDOW, loop over 8 heads ----------
// Writes bf16 attn output back into the q buffer region (block-local rows -> race-free).
__global__ __launch_bounds__(256) void attn_fused(
    const unsigned short* __restrict__ qbf, const unsigned short* __restrict__ kvbf,
    const float* __restrict__ bias_table, const int* __restrict__ mask_left,
    const int* __restrict__ mask_right, unsigned short* __restrict__ aout)
{
    __shared__ __align__(16) unsigned short Qn[64 * 32];    // [n][d] natural
    __shared__ __align__(16) unsigned short Kn[128 * 32];   // [m][d] natural
    __shared__ __align__(16) unsigned short Vt[32 * 128];   // [d][m], swizzled ^((d&7)<<4)
    __shared__ __align__(16) unsigned short Pn[64 * 128];   // [n][m], swizzled ^((n&7)<<4)
    __shared__ float ballT[8 * 192];                        // bias table [h][rel]

    const int w = blockIdx.x;
    const int t = threadIdx.x;
    const int wave = t >> 6, lane = t & 63;
    const int lr = lane & 15, hi = lane >> 4;
    const int n0w = wave * 16;

    for (int i = t; i < 1536; i += 256) {
        const int hh = i / 192, r = i - hh * 192;
        ballT[i] = bias_table[r * 8 + hh];
    }

    const int wi = w & 255;
    const int* mbase = nullptr;
    if (wi < 2) mbase = mask_left + wi * (64 * 128);
    else if (wi >= 254) mbase = mask_right + (wi - 254) * (64 * 128);

    const float scale = 0.17677669529663687f;  // 32^-0.5

    for (int h = 0; h < 8; ++h) {
        __syncthreads();   // prior iteration's LDS reads complete (and ballT before first use)
        {   // stage Q head-slice: [64][32]
            const int n = t >> 2, dq = t & 3;
            const uint4 v = *(const uint4*)(qbf + ((size_t)(w * 64 + n)) * 256 + h * 32 + dq * 8);
            *(uint4*)((char*)Qn + n * 64 + dq * 16) = v;
        }
        #pragma unroll
        for (int i = 0; i < 2; ++i) {   // stage K: [128][32]
            const int m = (t >> 2) + 64 * i, dq = t & 3;
            const uint4 v = *(const uint4*)(kvbf + ((size_t)(w * 128 + m)) * 512 + h * 32 + dq * 8);
            *(uint4*)((char*)Kn + m * 64 + dq * 16) = v;
        }
        #pragma unroll
        for (int i = 0; i < 2; ++i) {   // stage V transposed: Vt[d][m] swizzled
            const int db = (t >> 7) * 2 + i, m = t & 127;
            const uint4 v = *(const uint4*)(kvbf + ((size_t)(w * 128 + m)) * 512 + 256 + h * 32 + db * 8);
            const unsigned short* vs = (const unsigned short*)&v;
            #pragma unroll
            for (int e = 0; e < 8; ++e) {
                const int d = db * 8 + e;
                *(unsigned short*)((char*)Vt + d * 256 + ((2 * m) ^ ((d & 7) << 4))) = vs[e];
            }
        }
        __syncthreads();

        // S = Q K^T : wave handles rows n0w..n0w+15, all 128 cols
        const bf16x8 qa = *(const bf16x8*)((char*)Qn + (n0w + lr) * 64 + 16 * hi);
        f32x4 sacc[8];
        #pragma unroll
        for (int mj = 0; mj < 8; ++mj) {
            sacc[mj] = (f32x4){0.f, 0.f, 0.f, 0.f};
            const bf16x8 kb = *(const bf16x8*)((char*)Kn + (mj * 16 + lr) * 64 + 16 * hi);
            sacc[mj] = __builtin_amdgcn_mfma_f32_16x16x32_bf16(qa, kb, sacc[mj], 0, 0, 0);
        }

        // epilogue on C-layout: row n = n0w + 4*hi + q, col m = 16*mj + lr
        const float* bh = ballT + h * 192;
        #pragma unroll
        for (int mj = 0; mj < 8; ++mj) {
            const int m = 16 * mj + lr;
            #pragma unroll
            for (int q = 0; q < 4; ++q) {
                const int n = n0w + 4 * hi + q;
                sacc[mj][q] = fmaf(sacc[mj][q], scale, bh[n - m + 128]);
            }
        }
        if (mbase) {
            #pragma unroll
            for (int mj = 0; mj < 8; ++mj) {
                const int m = 16 * mj + lr;
                #pragma unroll
                for (int q = 0; q < 4; ++q) {
                    const int n = n0w + 4 * hi + q;
                    if (mbase[n * 128 + m] == 1) sacc[mj][q] = -FLT_MAX;
                }
            }
        }

        // softmax over m (per row): row lives in 16 lanes sharing hi -> shfl_xor 1,2,4,8
        float inv[4];
        #pragma unroll
        for (int q = 0; q < 4; ++q) {
            float mx = sacc[0][q];
            #pragma unroll
            for (int mj = 1; mj < 8; ++mj) mx = fmaxf(mx, sacc[mj][q]);
            mx = fmaxf(mx, __shfl_xor(mx, 1));
            mx = fmaxf(mx, __shfl_xor(mx, 2));
            mx = fmaxf(mx, __shfl_xor(mx, 4));
            mx = fmaxf(mx, __shfl_xor(mx, 8));
            float sm = 0.f;
            #pragma unroll
            for (int mj = 0; mj < 8; ++mj) {
                sacc[mj][q] = __expf(sacc[mj][q] - mx);
                sm += sacc[mj][q];
            }
            sm += __shfl_xor(sm, 1);
            sm += __shfl_xor(sm, 2);
            sm += __shfl_xor(sm, 4);
            sm += __shfl_xor(sm, 8);
            inv[q] = 1.0f / sm;
        }

        // write unnormalized P bf16 to Pn (pair even/odd lanes -> u32 stores); wave-local rows
        #pragma unroll
        for (int mj = 0; mj < 8; ++mj) {
            #pragma unroll
            for (int q = 0; q < 4; ++q) {
                const float pv = sacc[mj][q];
                const float po = __shfl_xor(pv, 1);
                if (!(lane & 1)) {
                    const int n = n0w + 4 * hi + q;
                    const int m = 16 * mj + lr;   // even
                    const unsigned int u = f2bf(pv) | (f2bf(po) << 16);
                    *(unsigned int*)((char*)Pn + n * 256 + ((2 * m) ^ ((n & 7) << 4))) = u;
                }
            }
        }
        // no barrier needed: each wave reads only its own Pn rows (compiler orders same-wave LDS)

        // O = P V : rows n0w..+15, cols d 0..31 (j=0,1)
        f32x4 oacc[2];
        oacc[0] = (f32x4){0.f, 0.f, 0.f, 0.f};
        oacc[1] = (f32x4){0.f, 0.f, 0.f, 0.f};
        const int nA = n0w + lr;                 // A-frag row
        const int swzA = (nA & 7) << 4;
        #pragma unroll
        for (int kk = 0; kk < 4; ++kk) {
            const bf16x8 pa = *(const bf16x8*)((char*)Pn + nA * 256 + ((64 * kk + 16 * hi) ^ swzA));
            #pragma unroll
            for (int j = 0; j < 2; ++j) {
                const int d = j * 16 + lr;
                const bf16x8 vb = *(const bf16x8*)((char*)Vt + d * 256 + ((64 * kk + 16 * hi) ^ ((d & 7) << 4)));
                oacc[j] = __builtin_amdgcn_mfma_f32_16x16x32_bf16(pa, vb, oacc[j], 0, 0, 0);
            }
        }
        // store bf16 into aout (the q region): row n = n0w+4*hi+q, col h*32 + j*16 + lr
        #pragma unroll
        for (int j = 0; j < 2; ++j) {
            #pragma unroll
            for (int q = 0; q < 4; ++q) {
                const int n = n0w + 4 * hi + q;
                aout[((size_t)(w * 64 + n)) * 256 + h * 32 + j * 16 + lr] =
                    (unsigned short)f2bf(oacc[j][q] * inv[q]);
            }
        }
    }
}

extern "C" void kernel_launch(void* const* d_in, const int* in_sizes, int n_in,
                              void* d_out, int out_size, void* d_ws, size_t ws_size,
                              hipStream_t stream)
{
    const float* x      = (const float*)d_in[0];   // (1024,64,256) f32
    const float* x_     = (const float*)d_in[1];   // (1024,128,256) f32
    const int*   mask_l = (const int*)d_in[2];
    const int*   mask_r = (const int*)d_in[3];
    const float* q_w    = (const float*)d_in[5];
    const float* q_b    = (const float*)d_in[6];
    const float* kv_w   = (const float*)d_in[7];
    const float* kv_b   = (const float*)d_in[8];
    const float* proj_w = (const float*)d_in[9];
    const float* proj_b = (const float*)d_in[10];
    const float* bias_t = (const float*)d_in[11];  // (192,8)

    // ws: qbf bf16 [65536][256] (32 MiB; later overwritten with bf16 attn-out) | kvbf bf16 [131072][512] (128 MiB)
    unsigned short* qbf  = (unsigned short*)d_ws;
    unsigned short* kvbf = qbf + (size_t)65536 * 256;
    float* out = (float*)d_out;

    prep_wt<<<1024, 256, 0, stream>>>(q_w, kv_w, proj_w);
    gemm_p<256, 0,      false, false><<<1024, 512, 0, stream>>>(x,  q_b,  qbf);
    gemm_p<512, 65536,  false, false><<<4096, 512, 0, stream>>>(x_, kv_b, kvbf);
    attn_fused<<<1024, 256, 0, stream>>>(qbf, kvbf, bias_t, mask_l, mask_r, qbf);
    gemm_p<256, 196608, true,  true ><<<1024, 512, 0, stream>>>(qbf, proj_b, out);
}

// Round 10
// 302.225 us; speedup vs baseline: 1.2132x; 1.2132x over previous
//
#include <hip/hip_runtime.h>
#include <float.h>

// B_=1024 windows, N=64, M=128, H=8, D=32, DIM=256, nW=256
// rel bias index: rel = n - m + 128 in [1,191]
// masks: wi in {0,1} -> mask_left[wi], wi in {254,255} -> mask_right[wi-254]

typedef __attribute__((ext_vector_type(8))) short bf16x8;
typedef __attribute__((ext_vector_type(4))) float f32x4;

static __device__ __forceinline__ unsigned int f2bf(float f) {
    unsigned int u = __float_as_uint(f);
    return (u + 0x7FFFu + ((u >> 16) & 1u)) >> 16;  // RNE
}
static __device__ __forceinline__ unsigned int pack2(float lo, float hi) {
    return f2bf(lo) | (f2bf(hi) << 16);
}

// Pre-swizzled bf16 weight tile images. Each 64x32 W-tile is stored as its exact
// 4 KiB LDS image (Ws[col][k] bf16, byte ^= ((col&3)<<4) within the 64-B row) so
// kernel staging is a linear 16 B/lane copy. Regions (shorts): q @0, kv @65536, proj @196608.
__device__ unsigned short g_Wt[262144];

__global__ __launch_bounds__(256) void prep_wt(
    const float* __restrict__ q_w, const float* __restrict__ kv_w, const float* __restrict__ proj_w)
{
    const int gid = blockIdx.x * 256 + threadIdx.x;
    int rel, ncs; const float* src;
    if (gid < 65536)       { rel = gid;          src = q_w;    ncs = 256; }
    else if (gid < 196608) { rel = gid - 65536;  src = kv_w;   ncs = 512; }
    else                   { rel = gid - 196608; src = proj_w; ncs = 256; }
    const int tl = rel >> 11, i = rel & 2047;      // tile = ct*8 + ks ; i = short idx in tile
    const int ct = tl >> 3,  ks = tl & 7;
    const int col = i >> 5,  si = i & 31;
    const int kl = ((2 * si) ^ ((col & 3) << 4)) >> 1;   // inverse swizzle (bits 4-5) -> source k
    g_Wt[gid] = (unsigned short)f2bf(src[(ks * 32 + kl) * ncs + ct * 64 + col]);
}

// ---------- pipelined MFMA GEMM: C[rows x NC] = A[rows x 256] @ W + bias ----------
// Tile 128x64, BK=32, dbuf LDS 24 KiB, 256 threads = 4 waves (2x2), wave tile 64x32.
// 8 K-steps, 1 barrier/step, 1-step register lookahead. ~5 blocks/CU -> cross-block
// TLP hides HBM latency (blocks don't share barriers).
// XCD swizzle: all col-tiles of a row-tile on one XCD (A L2-shared, HBM-fetched once).
template<int NC, int WT_OFF, bool ABF16, bool F32OUT>
__global__ __launch_bounds__(256) void gemm_t(
    const void* __restrict__ Ain, const float* __restrict__ bias, void* __restrict__ Cout)
{
    constexpr int NCT = NC / 64;
    __shared__ __align__(16) unsigned short As[2][4096];   // [buf][128 rows][32 k] swizzled
    __shared__ __align__(16) unsigned short Ws[2][2048];   // [buf] pre-swizzled 64x32 image

    const int nbx = 8 * NCT;
    const int g = blockIdx.x / nbx, r = blockIdx.x % nbx;
    const int bn = r >> 3, bm = g * 8 + (r & 7);
    const size_t r0 = (size_t)bm * 128;
    const int c0 = bn * 64;

    const int t = threadIdx.x;
    const int wave = t >> 6, lane = t & 63;
    const int lr = lane & 15, hi = lane >> 4;
    const int rw = (wave >> 1) * 64, cw = (wave & 1) * 32;

    const int arow = t >> 1, aseg = t & 1;                   // A staging: row, 16-elem k-seg
    const int aswz = (arow & 3) << 4;
    const int ao0 = (aseg * 32) ^ aswz, ao1 = (aseg * 32 + 16) ^ aswz;

    f32x4 acc[4][2];
    #pragma unroll
    for (int i = 0; i < 4; ++i)
        #pragma unroll
        for (int j = 0; j < 2; ++j) acc[i][j] = (f32x4){0.f, 0.f, 0.f, 0.f};

    float4 ra0, ra1, ra2, ra3;   // f32 A staging (16 floats)
    uint4  rb0, rb1;             // bf16 A staging (16 shorts)
    uint4  rwv;                  // W staging (8 shorts)

#define GLOAD(S)                                                                           \
    {                                                                                      \
        rwv = *(const uint4*)(g_Wt + WT_OFF + ((size_t)(bn * 8 + (S)) << 11) + t * 8);     \
        if (ABF16) {                                                                       \
            const unsigned short* asrc = (const unsigned short*)Ain + (r0 + arow) * 256 + (S) * 32 + aseg * 16; \
            rb0 = *(const uint4*)asrc; rb1 = *(const uint4*)(asrc + 8);                    \
        } else {                                                                           \
            const float* asrc = (const float*)Ain + (r0 + arow) * 256 + (S) * 32 + aseg * 16; \
            ra0 = *(const float4*)asrc;       ra1 = *(const float4*)(asrc + 4);            \
            ra2 = *(const float4*)(asrc + 8); ra3 = *(const float4*)(asrc + 12);           \
        }                                                                                  \
    }

#define SWRITE(B)                                                                          \
    {                                                                                      \
        uint4 u0, u1;                                                                      \
        if (ABF16) { u0 = rb0; u1 = rb1; }                                                 \
        else {                                                                             \
            u0 = make_uint4(pack2(ra0.x, ra0.y), pack2(ra0.z, ra0.w),                      \
                            pack2(ra1.x, ra1.y), pack2(ra1.z, ra1.w));                     \
            u1 = make_uint4(pack2(ra2.x, ra2.y), pack2(ra2.z, ra2.w),                      \
                            pack2(ra3.x, ra3.y), pack2(ra3.z, ra3.w));                     \
        }                                                                                  \
        char* ad = (char*)As[B] + arow * 64;                                               \
        *(uint4*)(ad + ao0) = u0; *(uint4*)(ad + ao1) = u1;                                \
        *(uint4*)((char*)Ws[B] + t * 16) = rwv;                                            \
    }

#define COMPUTE(B)                                                                         \
    {                                                                                      \
        const char* Ab = (const char*)As[B];                                               \
        const char* Wb = (const char*)Ws[B];                                               \
        const int ko = (16 * hi) ^ ((lr & 3) << 4);                                        \
        bf16x8 af0 = *(const bf16x8*)(Ab + (rw +      lr) * 64 + ko);                      \
        bf16x8 af1 = *(const bf16x8*)(Ab + (rw + 16 + lr) * 64 + ko);                      \
        bf16x8 af2 = *(const bf16x8*)(Ab + (rw + 32 + lr) * 64 + ko);                      \
        bf16x8 af3 = *(const bf16x8*)(Ab + (rw + 48 + lr) * 64 + ko);                      \
        bf16x8 bg0 = *(const bf16x8*)(Wb + (cw +      lr) * 64 + ko);                      \
        bf16x8 bg1 = *(const bf16x8*)(Wb + (cw + 16 + lr) * 64 + ko);                      \
        acc[0][0] = __builtin_amdgcn_mfma_f32_16x16x32_bf16(af0, bg0, acc[0][0], 0, 0, 0); \
        acc[0][1] = __builtin_amdgcn_mfma_f32_16x16x32_bf16(af0, bg1, acc[0][1], 0, 0, 0); \
        acc[1][0] = __builtin_amdgcn_mfma_f32_16x16x32_bf16(af1, bg0, acc[1][0], 0, 0, 0); \
        acc[1][1] = __builtin_amdgcn_mfma_f32_16x16x32_bf16(af1, bg1, acc[1][1], 0, 0, 0); \
        acc[2][0] = __builtin_amdgcn_mfma_f32_16x16x32_bf16(af2, bg0, acc[2][0], 0, 0, 0); \
        acc[2][1] = __builtin_amdgcn_mfma_f32_16x16x32_bf16(af2, bg1, acc[2][1], 0, 0, 0); \
        acc[3][0] = __builtin_amdgcn_mfma_f32_16x16x32_bf16(af3, bg0, acc[3][0], 0, 0, 0); \
        acc[3][1] = __builtin_amdgcn_mfma_f32_16x16x32_bf16(af3, bg1, acc[3][1], 0, 0, 0); \
    }

    GLOAD(0); SWRITE(0); __syncthreads();

    #pragma unroll 8
    for (int s = 0; s < 8; ++s) {
        if (s < 7) GLOAD(s + 1);            // issue next-step loads early
        COMPUTE(s & 1);
        if (s < 7) {
            SWRITE((s + 1) & 1);            // other buffer: last read in step s-1, safe
            __syncthreads();                // publish for step s+1
        }
    }

#undef GLOAD
#undef SWRITE
#undef COMPUTE

    // epilogue: row = r0+rw+i*16+4*hi+q, col = c0+cw+bj*16+lr
    #pragma unroll
    for (int i = 0; i < 4; ++i) {
        #pragma unroll
        for (int bj = 0; bj < 2; ++bj) {
            const int col = c0 + cw + bj * 16 + lr;
            const float bb = bias[col];
            #pragma unroll
            for (int q = 0; q < 4; ++q) {
                const size_t row = r0 + rw + i * 16 + 4 * hi + q;
                const float val = acc[i][bj][q] + bb;
                if (F32OUT) ((float*)Cout)[row * NC + col] = val;
                else        ((unsigned short*)Cout)[row * NC + col] = (unsigned short)f2bf(val);
            }
        }
    }
}

// ---------- fused MFMA attention: one block per WINDOW, loop over 8 heads ----------
// Writes bf16 attn output back into the q buffer region (block-local rows -> race-free).
__global__ __launch_bounds__(256) void attn_fused(
    const unsigned short* __restrict__ qbf, const unsigned short* __restrict__ kvbf,
    const float* __restrict__ bias_table, const int* __restrict__ mask_left,
    const int* __restrict__ mask_right, unsigned short* __restrict__ aout)
{
    __shared__ __align__(16) unsigned short Qn[64 * 32];    // [n][d] natural
    __shared__ __align__(16) unsigned short Kn[128 * 32];   // [m][d] natural
    __shared__ __align__(16) unsigned short Vt[32 * 128];   // [d][m], swizzled ^((d&7)<<4)
    __shared__ __align__(16) unsigned short Pn[64 * 128];   // [n][m], swizzled ^((n&7)<<4)
    __shared__ float ballT[8 * 192];                        // bias table [h][rel]

    const int w = blockIdx.x;
    const int t = threadIdx.x;
    const int wave = t >> 6, lane = t & 63;
    const int lr = lane & 15, hi = lane >> 4;
    const int n0w = wave * 16;

    for (int i = t; i < 1536; i += 256) {
        const int hh = i / 192, r = i - hh * 192;
        ballT[i] = bias_table[r * 8 + hh];
    }

    const int wi = w & 255;
    const int* mbase = nullptr;
    if (wi < 2) mbase = mask_left + wi * (64 * 128);
    else if (wi >= 254) mbase = mask_right + (wi - 254) * (64 * 128);

    const float scale = 0.17677669529663687f;  // 32^-0.5

    for (int h = 0; h < 8; ++h) {
        __syncthreads();   // prior iteration's LDS reads complete (and ballT before first use)
        {   // stage Q head-slice: [64][32]
            const int n = t >> 2, dq = t & 3;
            const uint4 v = *(const uint4*)(qbf + ((size_t)(w * 64 + n)) * 256 + h * 32 + dq * 8);
            *(uint4*)((char*)Qn + n * 64 + dq * 16) = v;
        }
        #pragma unroll
        for (int i = 0; i < 2; ++i) {   // stage K: [128][32]
            const int m = (t >> 2) + 64 * i, dq = t & 3;
            const uint4 v = *(const uint4*)(kvbf + ((size_t)(w * 128 + m)) * 512 + h * 32 + dq * 8);
            *(uint4*)((char*)Kn + m * 64 + dq * 16) = v;
        }
        #pragma unroll
        for (int i = 0; i < 2; ++i) {   // stage V transposed: Vt[d][m] swizzled
            const int db = (t >> 7) * 2 + i, m = t & 127;
            const uint4 v = *(const uint4*)(kvbf + ((size_t)(w * 128 + m)) * 512 + 256 + h * 32 + db * 8);
            const unsigned short* vs = (const unsigned short*)&v;
            #pragma unroll
            for (int e = 0; e < 8; ++e) {
                const int d = db * 8 + e;
                *(unsigned short*)((char*)Vt + d * 256 + ((2 * m) ^ ((d & 7) << 4))) = vs[e];
            }
        }
        __syncthreads();

        // S = Q K^T : wave handles rows n0w..n0w+15, all 128 cols
        const bf16x8 qa = *(const bf16x8*)((char*)Qn + (n0w + lr) * 64 + 16 * hi);
        f32x4 sacc[8];
        #pragma unroll
        for (int mj = 0; mj < 8; ++mj) {
            sacc[mj] = (f32x4){0.f, 0.f, 0.f, 0.f};
            const bf16x8 kb = *(const bf16x8*)((char*)Kn + (mj * 16 + lr) * 64 + 16 * hi);
            sacc[mj] = __builtin_amdgcn_mfma_f32_16x16x32_bf16(qa, kb, sacc[mj], 0, 0, 0);
        }

        // epilogue on C-layout: row n = n0w + 4*hi + q, col m = 16*mj + lr
        const float* bh = ballT + h * 192;
        #pragma unroll
        for (int mj = 0; mj < 8; ++mj) {
            const int m = 16 * mj + lr;
            #pragma unroll
            for (int q = 0; q < 4; ++q) {
                const int n = n0w + 4 * hi + q;
                sacc[mj][q] = fmaf(sacc[mj][q], scale, bh[n - m + 128]);
            }
        }
        if (mbase) {
            #pragma unroll
            for (int mj = 0; mj < 8; ++mj) {
                const int m = 16 * mj + lr;
                #pragma unroll
                for (int q = 0; q < 4; ++q) {
                    const int n = n0w + 4 * hi + q;
                    if (mbase[n * 128 + m] == 1) sacc[mj][q] = -FLT_MAX;
                }
            }
        }

        // softmax over m (per row): row lives in 16 lanes sharing hi -> shfl_xor 1,2,4,8
        float inv[4];
        #pragma unroll
        for (int q = 0; q < 4; ++q) {
            float mx = sacc[0][q];
            #pragma unroll
            for (int mj = 1; mj < 8; ++mj) mx = fmaxf(mx, sacc[mj][q]);
            mx = fmaxf(mx, __shfl_xor(mx, 1));
            mx = fmaxf(mx, __shfl_xor(mx, 2));
            mx = fmaxf(mx, __shfl_xor(mx, 4));
            mx = fmaxf(mx, __shfl_xor(mx, 8));
            float sm = 0.f;
            #pragma unroll
            for (int mj = 0; mj < 8; ++mj) {
                sacc[mj][q] = __expf(sacc[mj][q] - mx);
                sm += sacc[mj][q];
            }
            sm += __shfl_xor(sm, 1);
            sm += __shfl_xor(sm, 2);
            sm += __shfl_xor(sm, 4);
            sm += __shfl_xor(sm, 8);
            inv[q] = 1.0f / sm;
        }

        // write unnormalized P bf16 to Pn (pair even/odd lanes -> u32 stores); wave-local rows
        #pragma unroll
        for (int mj = 0; mj < 8; ++mj) {
            #pragma unroll
            for (int q = 0; q < 4; ++q) {
                const float pv = sacc[mj][q];
                const float po = __shfl_xor(pv, 1);
                if (!(lane & 1)) {
                    const int n = n0w + 4 * hi + q;
                    const int m = 16 * mj + lr;   // even
                    const unsigned int u = f2bf(pv) | (f2bf(po) << 16);
                    *(unsigned int*)((char*)Pn + n * 256 + ((2 * m) ^ ((n & 7) << 4))) = u;
                }
            }
        }
        // no barrier needed: each wave reads only its own Pn rows (compiler orders same-wave LDS)

        // O = P V : rows n0w..+15, cols d 0..31 (j=0,1)
        f32x4 oacc[2];
        oacc[0] = (f32x4){0.f, 0.f, 0.f, 0.f};
        oacc[1] = (f32x4){0.f, 0.f, 0.f, 0.f};
        const int nA = n0w + lr;                 // A-frag row
        const int swzA = (nA & 7) << 4;
        #pragma unroll
        for (int kk = 0; kk < 4; ++kk) {
            const bf16x8 pa = *(const bf16x8*)((char*)Pn + nA * 256 + ((64 * kk + 16 * hi) ^ swzA));
            #pragma unroll
            for (int j = 0; j < 2; ++j) {
                const int d = j * 16 + lr;
                const bf16x8 vb = *(const bf16x8*)((char*)Vt + d * 256 + ((64 * kk + 16 * hi) ^ ((d & 7) << 4)));
                oacc[j] = __builtin_amdgcn_mfma_f32_16x16x32_bf16(pa, vb, oacc[j], 0, 0, 0);
            }
        }
        // store bf16 into aout (the q region): row n = n0w+4*hi+q, col h*32 + j*16 + lr
        #pragma unroll
        for (int j = 0; j < 2; ++j) {
            #pragma unroll
            for (int q = 0; q < 4; ++q) {
                const int n = n0w + 4 * hi + q;
                aout[((size_t)(w * 64 + n)) * 256 + h * 32 + j * 16 + lr] =
                    (unsigned short)f2bf(oacc[j][q] * inv[q]);
            }
        }
    }
}

extern "C" void kernel_launch(void* const* d_in, const int* in_sizes, int n_in,
                              void* d_out, int out_size, void* d_ws, size_t ws_size,
                              hipStream_t stream)
{
    const float* x      = (const float*)d_in[0];   // (1024,64,256) f32
    const float* x_     = (const float*)d_in[1];   // (1024,128,256) f32
    const int*   mask_l = (const int*)d_in[2];
    const int*   mask_r = (const int*)d_in[3];
    const float* q_w    = (const float*)d_in[5];
    const float* q_b    = (const float*)d_in[6];
    const float* kv_w   = (const float*)d_in[7];
    const float* kv_b   = (const float*)d_in[8];
    const float* proj_w = (const float*)d_in[9];
    const float* proj_b = (const float*)d_in[10];
    const float* bias_t = (const float*)d_in[11];  // (192,8)

    // ws: qbf bf16 [65536][256] (32 MiB; later overwritten with bf16 attn-out) | kvbf bf16 [131072][512] (128 MiB)
    unsigned short* qbf  = (unsigned short*)d_ws;
    unsigned short* kvbf = qbf + (size_t)65536 * 256;
    float* out = (float*)d_out;

    prep_wt<<<1024, 256, 0, stream>>>(q_w, kv_w, proj_w);
    gemm_t<256, 0,      false, false><<<2048, 256, 0, stream>>>(x,  q_b,  qbf);
    gemm_t<512, 65536,  false, false><<<8192, 256, 0, stream>>>(x_, kv_b, kvbf);
    attn_fused<<<1024, 256, 0, stream>>>(qbf, kvbf, bias_t, mask_l, mask_r, qbf);
    gemm_t<256, 196608, true,  true ><<<2048, 256, 0, stream>>>(qbf, proj_b, out);
}